// Round 14
// baseline (121.085 us; speedup 1.0000x reference)
//
#include <hip/hip_runtime.h>
#include <hip/hip_bf16.h>
#include <math.h>

#define H_DIM 288
#define NHEADS 18
#define HEAD_D 16
#define SEQ 2048
#define BATCH 2
#define M_TOT (BATCH*SEQ)       // 4096
#define XCNT (M_TOT*H_DIM)      // 1179648
#define WCNT (H_DIM*H_DIM)      // 82944
#define NUNITS 5184             // 36 bh x 144 (qq,chunk) split-K units (64q)
#define NRED 1152               // 36 bh x 32 qq reduction waves

typedef _Float16 f16_t;
typedef __attribute__((ext_vector_type(2))) _Float16 half2v;
typedef __attribute__((ext_vector_type(4))) _Float16 half4v;
typedef __attribute__((ext_vector_type(8))) _Float16 half8v;
typedef __attribute__((ext_vector_type(4))) float   float4v;

// ---------------------------------------------------------------------------
// K0: fp32 -> f16 convert: X (4096x288) and the four 288x288 weights.
// ---------------------------------------------------------------------------
__global__ __launch_bounds__(256) void cvt_f16(
    const float* __restrict__ X,
    const float* __restrict__ Wq, const float* __restrict__ Wk,
    const float* __restrict__ Wv, const float* __restrict__ Wo,
    f16_t* __restrict__ Xf, f16_t* __restrict__ Wf)
{
    int idx = blockIdx.x * 256 + threadIdx.x;
    const int X4 = XCNT/4, W4 = WCNT/4;
    if (idx >= X4 + 4*W4) return;
    const float* src; f16_t* dst; int off;
    if (idx < X4) { src = X; dst = Xf; off = idx; }
    else {
        int r = idx - X4;
        int wz = r / W4; off = r - wz*W4;
        src = (wz==0) ? Wq : (wz==1) ? Wk : (wz==2) ? Wv : Wo;
        dst = Wf + (size_t)wz*WCNT;
    }
    float4 v = ((const float4*)src)[off];
    half4v h; h[0]=(f16_t)v.x; h[1]=(f16_t)v.y; h[2]=(f16_t)v.z; h[3]=(f16_t)v.w;
    ((half4v*)dst)[off] = h;
}

// ---------------------------------------------------------------------------
// K1: QKV projection via MFMA 16x16x32 f16 (R13-proven). One wave/block,
// tile M=32 x N=48, grid (18,128). RoPE via HW v_sin/v_cos in revolutions.
// Q pre-scaled 0.25*log2(e); V -> tiled Vt[bh][s>>4][d][s&15].
// ---------------------------------------------------------------------------
__global__ __launch_bounds__(64) void qkv_mfma(
    const f16_t* __restrict__ Xf, const f16_t* __restrict__ Wf,
    f16_t* __restrict__ Q16, f16_t* __restrict__ K16, f16_t* __restrict__ Vt)
{
    const int bx = blockIdx.x;          // 0..17
    const int z  = bx/6;
    const int n0 = (bx - z*6)*48;
    const int m0 = blockIdx.y*32;
    const int lane = threadIdx.x & 63;
    const int n = lane & 15, quad = lane >> 4;

    const f16_t* W = Wf + (size_t)z*WCNT;

    float4v acc[2][3];
    #pragma unroll
    for (int mt = 0; mt < 2; mt++)
        #pragma unroll
        for (int nt = 0; nt < 3; nt++)
            acc[mt][nt] = (float4v){0.f,0.f,0.f,0.f};

    for (int k0 = 0; k0 < H_DIM; k0 += 32) {
        half8v a[2], b[3];
        #pragma unroll
        for (int mt = 0; mt < 2; mt++)
            a[mt] = *(const half8v*)(Xf + (size_t)(m0 + mt*16 + n)*H_DIM + k0 + quad*8);
        #pragma unroll
        for (int nt = 0; nt < 3; nt++)
            b[nt] = *(const half8v*)(W + (size_t)(n0 + nt*16 + n)*H_DIM + k0 + quad*8);
        #pragma unroll
        for (int mt = 0; mt < 2; mt++)
            #pragma unroll
            for (int nt = 0; nt < 3; nt++)
                acc[mt][nt] = __builtin_amdgcn_mfma_f32_16x16x32_f16(a[mt], b[nt], acc[mt][nt], 0, 0, 0);
    }

    if (z < 2) {   // Q or K: RoPE epilogue
        f16_t* dst = (z == 0) ? Q16 : K16;
        const float invf_rev = exp2f(-1.6609640474436813f * (float)(n & 7))
                             * 0.15915494309189535f;
        #pragma unroll
        for (int mt = 0; mt < 2; mt++) {
            #pragma unroll
            for (int r = 0; r < 4; r++) {
                int m = m0 + mt*16 + quad*4 + r;
                int bb = m >> 11, s = m & (SEQ - 1);
                float rev = (float)s * invf_rev;
                float fr = rev - floorf(rev);
                float sn = __builtin_amdgcn_sinf(fr);
                float c  = __builtin_amdgcn_cosf(fr);
                #pragma unroll
                for (int nt = 0; nt < 3; nt++) {
                    float own = acc[mt][nt][r];
                    float par = __shfl_xor(own, 8, 64);
                    float val = (n & 8) ? fmaf(own, c, par*sn) : fmaf(own, c, -par*sn);
                    if (z == 0) val *= 0.36067376022224085f;  // 0.25 * log2(e)
                    int head = (n0 >> 4) + nt;
                    dst[((size_t)((bb*NHEADS + head)*SEQ) + s)*HEAD_D + n] = (f16_t)val;
                }
            }
        }
    } else {       // V: transposed tiled store
        #pragma unroll
        for (int mt = 0; mt < 2; mt++)
            #pragma unroll
            for (int nt = 0; nt < 3; nt++)
                #pragma unroll
                for (int r = 0; r < 4; r++) {
                    int m = m0 + mt*16 + quad*4 + r;
                    int bb = m >> 11, s = m & (SEQ - 1);
                    int head = (n0 >> 4) + nt;
                    Vt[(size_t)(bb*NHEADS + head)*(SEQ*HEAD_D)
                       + (size_t)(s >> 4)*256 + n*16 + (s & 15)] = (f16_t)acc[mt][nt][r];
                }
    }
}

__device__ __forceinline__ half4v pack4(const float p[4]) {
    half2v ab = __builtin_bit_cast(half2v, __builtin_amdgcn_cvt_pkrtz(p[0], p[1]));
    half2v cd = __builtin_bit_cast(half2v, __builtin_amdgcn_cvt_pkrtz(p[2], p[3]));
    half4v o; o[0]=ab[0]; o[1]=ab[1]; o[2]=cd[0]; o[3]=cd[1];
    return o;
}

// ---------------------------------------------------------------------------
// K2: flash attention split-K partials, 64 queries per unit (4 q-tiles share
// every K/V load -> K/V L2 traffic halved vs 32q). One wave per unit
// (bh, qq, chunk); chunk = 16 key tiles. Bulk path: all 32 loads up-front.
// Unit count per bh: qq groups g=qq>>2 (4 qq each), nch=g+1 -> 144 units.
// ---------------------------------------------------------------------------
__global__ __launch_bounds__(256) void attn_part(
    const f16_t* __restrict__ Q16, const f16_t* __restrict__ K16,
    const f16_t* __restrict__ Vt,
    float4* __restrict__ accbuf, float* __restrict__ lbuf)
{
    const int unit = blockIdx.x*4 + (threadIdx.x >> 6);   // 0..5183
    const int lane = threadIdx.x & 63;
    const int n = lane & 15, quad = lane >> 4;

    const int bh = unit / 144;
    const int rem = unit - bh*144;
    int g, t0;
    if      (rem < 4)   { g=0; t0=rem;     }
    else if (rem < 12)  { g=1; t0=rem-4;   }
    else if (rem < 24)  { g=2; t0=rem-12;  }
    else if (rem < 40)  { g=3; t0=rem-24;  }
    else if (rem < 60)  { g=4; t0=rem-40;  }
    else if (rem < 84)  { g=5; t0=rem-60;  }
    else if (rem < 112) { g=6; t0=rem-84;  }
    else                { g=7; t0=rem-112; }
    const int qd = t0 / (g+1);
    const int qq = 4*g + qd;            // 0..31: 64-query block index
    const int chunk = t0 - qd*(g+1);
    const int q0 = qq*64;

    half4v qb[4];
    #pragma unroll
    for (int t = 0; t < 4; t++)
        qb[t] = *(const half4v*)(Q16 + ((size_t)bh*SEQ + q0 + t*16 + n)*HEAD_D + quad*4);
    const f16_t* Kb = K16 + (size_t)bh * SEQ * HEAD_D;
    const f16_t* Vb = Vt  + (size_t)bh * SEQ * HEAD_D;
    const int loff = n*16 + quad*4;

    const float4v zero = {0.f, 0.f, 0.f, 0.f};
    float4v acc[4] = {zero, zero, zero, zero};
    float l[4] = {0.f, 0.f, 0.f, 0.f};

    const int lim3 = 4*qq + 3;          // diag of tile t at kt == 4*qq + t
    const int ktlo = chunk*16;
    const int kthi = min(ktlo + 15, lim3);

    if (ktlo + 15 < 4*qq) {
        // Bulk: full 16-tile chunk, all 4 q-tiles active and unmasked.
        half4v KA[16], VA[16];
        #pragma unroll
        for (int i = 0; i < 16; i++) {
            KA[i] = *(const half4v*)(Kb + (size_t)(ktlo + i)*256 + loff);
            VA[i] = *(const half4v*)(Vb + (size_t)(ktlo + i)*256 + loff);
        }
        #pragma unroll
        for (int i = 0; i < 16; i++) {
            #pragma unroll
            for (int t = 0; t < 4; t++) {
                float4v s = __builtin_amdgcn_mfma_f32_16x16x16f16(KA[i], qb[t], zero, 0, 0, 0);
                float p[4];
                #pragma unroll
                for (int r = 0; r < 4; r++) p[r] = __builtin_amdgcn_exp2f(s[r]);
                l[t] += (p[0]+p[1]) + (p[2]+p[3]);
                acc[t] = __builtin_amdgcn_mfma_f32_16x16x16f16(VA[i], pack4(p), acc[t], 0, 0, 0);
            }
        }
    } else {
        // Boundary chunk: per-tile activity/mask checks (wave-uniform).
        int kt = ktlo;
        half4v ka = *(const half4v*)(Kb + (size_t)kt*256 + loff);
        half4v va = *(const half4v*)(Vb + (size_t)kt*256 + loff);
        for (; kt <= kthi; kt++) {
            half4v kan, van;
            if (kt < kthi) {
                kan = *(const half4v*)(Kb + (size_t)(kt+1)*256 + loff);
                van = *(const half4v*)(Vb + (size_t)(kt+1)*256 + loff);
            }
            #pragma unroll
            for (int t = 0; t < 4; t++) {
                const int lim = 4*qq + t;
                if (kt > lim) continue;
                float4v s = __builtin_amdgcn_mfma_f32_16x16x16f16(ka, qb[t], zero, 0, 0, 0);
                float p[4];
                if (kt == lim) {
                    #pragma unroll
                    for (int r = 0; r < 4; r++) {
                        float e = __builtin_amdgcn_exp2f(s[r]);
                        p[r] = (quad*4 + r <= n) ? e : 0.0f;
                    }
                } else {
                    #pragma unroll
                    for (int r = 0; r < 4; r++) p[r] = __builtin_amdgcn_exp2f(s[r]);
                }
                l[t] += (p[0]+p[1]) + (p[2]+p[3]);
                acc[t] = __builtin_amdgcn_mfma_f32_16x16x16f16(va, pack4(p), acc[t], 0, 0, 0);
            }
            ka = kan; va = van;
        }
    }

    #pragma unroll
    for (int t = 0; t < 4; t++) {
        float4 a; a.x=acc[t][0]; a.y=acc[t][1]; a.z=acc[t][2]; a.w=acc[t][3];
        accbuf[((size_t)unit*4 + t)*64 + lane] = a;
        lbuf[((size_t)unit*4 + t)*64 + lane] = l[t];
    }
}

// ---------------------------------------------------------------------------
// K3: reduction: one wave per (bh, qq) sums <=8 chunk partials for 4 tiles,
// normalizes, writes f16 O. ubase within bh: (g+1)*(2g+j), g=qq>>2, j=qq&3.
// ---------------------------------------------------------------------------
__global__ __launch_bounds__(256) void attn_red(
    const float4* __restrict__ accbuf, const float* __restrict__ lbuf,
    f16_t* __restrict__ Of)
{
    const int wid = blockIdx.x*4 + (threadIdx.x >> 6);    // 0..1151
    const int lane = threadIdx.x & 63;
    const int n = lane & 15, quad = lane >> 4;
    const int bh = wid >> 5, qq = wid & 31;
    const int b = bh / NHEADS, h = bh - b*NHEADS;
    const int g = qq >> 2, j = qq & 3;
    const int nch = g + 1;
    const int ubase = bh*144 + (g+1)*(2*g + j);

    #pragma unroll
    for (int t = 0; t < 4; t++) {
        float4 a = {0.f, 0.f, 0.f, 0.f};
        float l = 0.f;
        for (int c = 0; c < nch; c++) {
            size_t idx = ((size_t)(ubase + c)*4 + t)*64 + lane;
            float4 v = accbuf[idx];
            a.x += v.x; a.y += v.y; a.z += v.z; a.w += v.w;
            l += lbuf[idx];
        }
        l += __shfl_xor(l, 16, 64);
        l += __shfl_xor(l, 32, 64);
        float inv = 1.0f / l;
        half4v o;
        o[0]=(f16_t)(a.x*inv); o[1]=(f16_t)(a.y*inv);
        o[2]=(f16_t)(a.z*inv); o[3]=(f16_t)(a.w*inv);
        *(half4v*)(Of + (size_t)(b*SEQ + qq*64 + t*16 + n)*H_DIM + h*HEAD_D + quad*4) = o;
    }
}

// ---------------------------------------------------------------------------
// K4: output projection via MFMA (R13-proven). Tile M=32 x N=48, grid (6,128).
// ---------------------------------------------------------------------------
__global__ __launch_bounds__(64) void out_mfma(
    const f16_t* __restrict__ Of, const f16_t* __restrict__ Wo16,
    float* __restrict__ C)
{
    const int n0 = blockIdx.x * 48;
    const int m0 = blockIdx.y * 32;
    const int lane = threadIdx.x & 63;
    const int n = lane & 15, quad = lane >> 4;

    float4v acc[2][3];
    #pragma unroll
    for (int mt = 0; mt < 2; mt++)
        #pragma unroll
        for (int nt = 0; nt < 3; nt++)
            acc[mt][nt] = (float4v){0.f,0.f,0.f,0.f};

    for (int k0 = 0; k0 < H_DIM; k0 += 32) {
        half8v a[2], b[3];
        #pragma unroll
        for (int mt = 0; mt < 2; mt++)
            a[mt] = *(const half8v*)(Of + (size_t)(m0 + mt*16 + n)*H_DIM + k0 + quad*8);
        #pragma unroll
        for (int nt = 0; nt < 3; nt++)
            b[nt] = *(const half8v*)(Wo16 + (size_t)(n0 + nt*16 + n)*H_DIM + k0 + quad*8);
        #pragma unroll
        for (int mt = 0; mt < 2; mt++)
            #pragma unroll
            for (int nt = 0; nt < 3; nt++)
                acc[mt][nt] = __builtin_amdgcn_mfma_f32_16x16x32_f16(a[mt], b[nt], acc[mt][nt], 0, 0, 0);
    }
    #pragma unroll
    for (int mt = 0; mt < 2; mt++)
        #pragma unroll
        for (int nt = 0; nt < 3; nt++)
            #pragma unroll
            for (int r = 0; r < 4; r++) {
                int m = m0 + mt*16 + quad*4 + r;
                C[(size_t)m*H_DIM + n0 + nt*16 + n] = acc[mt][nt][r];
            }
}

// ---------------------------------------------------------------------------
extern "C" void kernel_launch(void* const* d_in, const int* in_sizes, int n_in,
                              void* d_out, int out_size, void* d_ws, size_t ws_size,
                              hipStream_t stream)
{
    const float* Xh = (const float*)d_in[0];
    const float* Wq = (const float*)d_in[1];
    const float* Wk = (const float*)d_in[2];
    const float* Wv = (const float*)d_in[3];
    const float* Wo = (const float*)d_in[4];
    float* out = (float*)d_out;

    f16_t* Xf  = (f16_t*)d_ws;                  // XCNT
    f16_t* Wf  = Xf + XCNT;                     // 4*WCNT
    f16_t* Q16 = Wf + 4*(size_t)WCNT;           // XCNT
    f16_t* K16 = Q16 + XCNT;                    // XCNT
    f16_t* Vt  = K16 + XCNT;                    // XCNT
    f16_t* Of  = Vt + XCNT;                     // XCNT
    float4* accbuf = (float4*)(Of + XCNT);      // NUNITS*4*64 float4
    float*  lbuf   = (float*)(accbuf + (size_t)NUNITS*4*64);

    const int total4 = (XCNT + 4*WCNT)/4;
    cvt_f16<<<dim3((total4 + 255)/256), 256, 0, stream>>>(Xh, Wq, Wk, Wv, Wo, Xf, Wf);
    qkv_mfma<<<dim3(18, 128), 64, 0, stream>>>(Xf, Wf, Q16, K16, Vt);
    attn_part<<<dim3(NUNITS/4), 256, 0, stream>>>(Q16, K16, Vt, accbuf, lbuf);
    attn_red<<<dim3(NRED/4), 256, 0, stream>>>(accbuf, lbuf, Of);
    out_mfma<<<dim3(6, 128), 64, 0, stream>>>(Of, Wf + 3*(size_t)WCNT, out);
}

// Round 15
// 112.421 us; speedup vs baseline: 1.0771x; 1.0771x over previous
//
#include <hip/hip_runtime.h>
#include <hip/hip_bf16.h>
#include <math.h>

#define H_DIM 288
#define NHEADS 18
#define HEAD_D 16
#define SEQ 2048
#define BATCH 2
#define M_TOT (BATCH*SEQ)       // 4096
#define XCNT (M_TOT*H_DIM)      // 1179648
#define WCNT (H_DIM*H_DIM)      // 82944
#define NUNITS 10368            // 36 bh x 288 (qp,chunk) split-K units
#define NQUNITS 2304            // 36 bh x 64 qp

typedef _Float16 f16_t;
typedef __attribute__((ext_vector_type(2))) _Float16 half2v;
typedef __attribute__((ext_vector_type(4))) _Float16 half4v;
typedef __attribute__((ext_vector_type(8))) _Float16 half8v;
typedef __attribute__((ext_vector_type(4))) float   float4v;

// ---------------------------------------------------------------------------
// K0: fp32 -> f16 convert: X (4096x288) and the four 288x288 weights.
// ---------------------------------------------------------------------------
__global__ __launch_bounds__(256) void cvt_f16(
    const float* __restrict__ X,
    const float* __restrict__ Wq, const float* __restrict__ Wk,
    const float* __restrict__ Wv, const float* __restrict__ Wo,
    f16_t* __restrict__ Xf, f16_t* __restrict__ Wf)
{
    int idx = blockIdx.x * 256 + threadIdx.x;
    const int X4 = XCNT/4, W4 = WCNT/4;
    if (idx >= X4 + 4*W4) return;
    const float* src; f16_t* dst; int off;
    if (idx < X4) { src = X; dst = Xf; off = idx; }
    else {
        int r = idx - X4;
        int wz = r / W4; off = r - wz*W4;
        src = (wz==0) ? Wq : (wz==1) ? Wk : (wz==2) ? Wv : Wo;
        dst = Wf + (size_t)wz*WCNT;
    }
    float4 v = ((const float4*)src)[off];
    half4v h; h[0]=(f16_t)v.x; h[1]=(f16_t)v.y; h[2]=(f16_t)v.z; h[3]=(f16_t)v.w;
    ((half4v*)dst)[off] = h;
}

// ---------------------------------------------------------------------------
// K1: QKV projection via MFMA 16x16x32 f16 (R9-proven tiling). One wave per
// block, tile M=32 x N=48, grid (18,128).
// Epilogue: Q,K -> RoPE -> f16 [b,h,s,d]; Q pre-scaled 0.25*log2(e) so the
// attention softmax can use raw exp2.
// RoPE sin/cos via HW v_sin/v_cos in REVOLUTIONS with explicit fract range
// reduction (replaces libm sincosf's slow large-arg path; err ~1e-4 rad).
// V -> f16 tiled Vt[bh][s>>4][d][s&15].
// ---------------------------------------------------------------------------
__global__ __launch_bounds__(64) void qkv_mfma(
    const f16_t* __restrict__ Xf, const f16_t* __restrict__ Wf,
    f16_t* __restrict__ Q16, f16_t* __restrict__ K16, f16_t* __restrict__ Vt)
{
    const int bx = blockIdx.x;          // 0..17
    const int z  = bx/6;
    const int n0 = (bx - z*6)*48;
    const int m0 = blockIdx.y*32;
    const int lane = threadIdx.x & 63;
    const int n = lane & 15, quad = lane >> 4;

    const f16_t* W = Wf + (size_t)z*WCNT;

    float4v acc[2][3];
    #pragma unroll
    for (int mt = 0; mt < 2; mt++)
        #pragma unroll
        for (int nt = 0; nt < 3; nt++)
            acc[mt][nt] = (float4v){0.f,0.f,0.f,0.f};

    for (int k0 = 0; k0 < H_DIM; k0 += 32) {
        half8v a[2], b[3];
        #pragma unroll
        for (int mt = 0; mt < 2; mt++)
            a[mt] = *(const half8v*)(Xf + (size_t)(m0 + mt*16 + n)*H_DIM + k0 + quad*8);
        #pragma unroll
        for (int nt = 0; nt < 3; nt++)
            b[nt] = *(const half8v*)(W + (size_t)(n0 + nt*16 + n)*H_DIM + k0 + quad*8);
        #pragma unroll
        for (int mt = 0; mt < 2; mt++)
            #pragma unroll
            for (int nt = 0; nt < 3; nt++)
                acc[mt][nt] = __builtin_amdgcn_mfma_f32_16x16x32_f16(a[mt], b[nt], acc[mt][nt], 0, 0, 0);
    }

    if (z < 2) {   // Q or K: RoPE epilogue
        f16_t* dst = (z == 0) ? Q16 : K16;
        // invf in revolutions: theta^{-(d%8)/8} / (2*pi)
        const float invf_rev = exp2f(-1.6609640474436813f * (float)(n & 7))
                             * 0.15915494309189535f;
        #pragma unroll
        for (int mt = 0; mt < 2; mt++) {
            #pragma unroll
            for (int r = 0; r < 4; r++) {
                int m = m0 + mt*16 + quad*4 + r;
                int bb = m >> 11, s = m & (SEQ - 1);
                float rev = (float)s * invf_rev;
                float fr = rev - floorf(rev);
                float sn = __builtin_amdgcn_sinf(fr);   // sin(2*pi*fr)
                float c  = __builtin_amdgcn_cosf(fr);
                #pragma unroll
                for (int nt = 0; nt < 3; nt++) {
                    float own = acc[mt][nt][r];
                    float par = __shfl_xor(own, 8, 64);
                    float val = (n & 8) ? fmaf(own, c, par*sn) : fmaf(own, c, -par*sn);
                    if (z == 0) val *= 0.36067376022224085f;  // 0.25 * log2(e)
                    int head = (n0 >> 4) + nt;
                    dst[((size_t)((bb*NHEADS + head)*SEQ) + s)*HEAD_D + n] = (f16_t)val;
                }
            }
        }
    } else {       // V: transposed tiled store
        #pragma unroll
        for (int mt = 0; mt < 2; mt++)
            #pragma unroll
            for (int nt = 0; nt < 3; nt++)
                #pragma unroll
                for (int r = 0; r < 4; r++) {
                    int m = m0 + mt*16 + quad*4 + r;
                    int bb = m >> 11, s = m & (SEQ - 1);
                    int head = (n0 >> 4) + nt;
                    Vt[(size_t)(bb*NHEADS + head)*(SEQ*HEAD_D)
                       + (size_t)(s >> 4)*256 + n*16 + (s & 15)] = (f16_t)acc[mt][nt][r];
                }
    }
}

__device__ __forceinline__ half4v pack4(const float p[4]) {
    half2v ab = __builtin_bit_cast(half2v, __builtin_amdgcn_cvt_pkrtz(p[0], p[1]));
    half2v cd = __builtin_bit_cast(half2v, __builtin_amdgcn_cvt_pkrtz(p[2], p[3]));
    half4v o; o[0]=ab[0]; o[1]=ab[1]; o[2]=cd[0]; o[3]=cd[1];
    return o;
}

// ---------------------------------------------------------------------------
// K2: flash attention split-K partials (R9-proven) + bulk path for full
// unmasked 16-tile chunks (all 32 K/V loads up-front; validated R10/R11).
// One wave per unit (bh, qp, chunk); partials to ws. No LDS.
// 32 queries/unit: more waves beats more reuse here (R8/R14 both confirmed
// the 64q/4-tile variant regresses via TLP loss + VGPR pressure).
// ---------------------------------------------------------------------------
__global__ __launch_bounds__(256) void attn_part(
    const f16_t* __restrict__ Q16, const f16_t* __restrict__ K16,
    const f16_t* __restrict__ Vt,
    float4* __restrict__ accbuf, float* __restrict__ lbuf)
{
    const int unit = blockIdx.x*4 + (threadIdx.x >> 6);   // 0..10367
    const int lane = threadIdx.x & 63;
    const int n = lane & 15, quad = lane >> 4;

    const int bh = unit / 288;
    const int rem = unit - bh*288;
    int g, t0;
    if      (rem < 8)   { g=0; t0=rem;     }
    else if (rem < 24)  { g=1; t0=rem-8;   }
    else if (rem < 48)  { g=2; t0=rem-24;  }
    else if (rem < 80)  { g=3; t0=rem-48;  }
    else if (rem < 120) { g=4; t0=rem-80;  }
    else if (rem < 168) { g=5; t0=rem-120; }
    else if (rem < 224) { g=6; t0=rem-168; }
    else                { g=7; t0=rem-224; }
    const int qd = t0 / (g+1);
    const int qp = 8*g + qd;
    const int chunk = t0 - qd*(g+1);
    const int q0 = qp*32;

    half4v qb0 = *(const half4v*)(Q16 + ((size_t)bh*SEQ + q0 + n)*HEAD_D + quad*4);
    half4v qb1 = *(const half4v*)(Q16 + ((size_t)bh*SEQ + q0 + 16 + n)*HEAD_D + quad*4);
    const f16_t* Kb = K16 + (size_t)bh * SEQ * HEAD_D;
    const f16_t* Vb = Vt  + (size_t)bh * SEQ * HEAD_D;
    const int loff = n*16 + quad*4;

    const float4v zero = {0.f, 0.f, 0.f, 0.f};
    float4v acc0 = zero, acc1 = zero;
    float l0 = 0.f, l1 = 0.f;

    const int lim0 = 2*qp, lim1 = 2*qp + 1;
    const int ktlo = chunk*16;
    const int kthi = min(ktlo + 15, lim1);

    if (ktlo + 15 < lim0) {
        half4v KA[16], VA[16];
        #pragma unroll
        for (int i = 0; i < 16; i++) {
            KA[i] = *(const half4v*)(Kb + (size_t)(ktlo + i)*256 + loff);
            VA[i] = *(const half4v*)(Vb + (size_t)(ktlo + i)*256 + loff);
        }
        #pragma unroll
        for (int i = 0; i < 16; i++) {
            float4v s1 = __builtin_amdgcn_mfma_f32_16x16x16f16(KA[i], qb1, zero, 0, 0, 0);
            float4v s0 = __builtin_amdgcn_mfma_f32_16x16x16f16(KA[i], qb0, zero, 0, 0, 0);
            float p1[4], p0[4];
            #pragma unroll
            for (int r = 0; r < 4; r++) { p1[r] = __builtin_amdgcn_exp2f(s1[r]); p0[r] = __builtin_amdgcn_exp2f(s0[r]); }
            l1 += (p1[0]+p1[1]) + (p1[2]+p1[3]);
            l0 += (p0[0]+p0[1]) + (p0[2]+p0[3]);
            acc1 = __builtin_amdgcn_mfma_f32_16x16x16f16(VA[i], pack4(p1), acc1, 0, 0, 0);
            acc0 = __builtin_amdgcn_mfma_f32_16x16x16f16(VA[i], pack4(p0), acc0, 0, 0, 0);
        }
    } else {
        int kt = ktlo;
        half4v ka = *(const half4v*)(Kb + (size_t)kt*256 + loff);
        half4v va = *(const half4v*)(Vb + (size_t)kt*256 + loff);
        for (; kt <= kthi; kt++) {
            half4v kan, van;
            if (kt < kthi) {
                kan = *(const half4v*)(Kb + (size_t)(kt+1)*256 + loff);
                van = *(const half4v*)(Vb + (size_t)(kt+1)*256 + loff);
            }
            {   // tile 1
                float4v s = __builtin_amdgcn_mfma_f32_16x16x16f16(ka, qb1, zero, 0, 0, 0);
                float p[4];
                #pragma unroll
                for (int r = 0; r < 4; r++) {
                    float e = __builtin_amdgcn_exp2f(s[r]);
                    p[r] = (kt == lim1 && quad*4 + r > n) ? 0.0f : e;
                }
                l1 += (p[0]+p[1]) + (p[2]+p[3]);
                acc1 = __builtin_amdgcn_mfma_f32_16x16x16f16(va, pack4(p), acc1, 0, 0, 0);
            }
            if (kt <= lim0) {   // tile 0
                float4v s = __builtin_amdgcn_mfma_f32_16x16x16f16(ka, qb0, zero, 0, 0, 0);
                float p[4];
                #pragma unroll
                for (int r = 0; r < 4; r++) {
                    float e = __builtin_amdgcn_exp2f(s[r]);
                    p[r] = (kt == lim0 && quad*4 + r > n) ? 0.0f : e;
                }
                l0 += (p[0]+p[1]) + (p[2]+p[3]);
                acc0 = __builtin_amdgcn_mfma_f32_16x16x16f16(va, pack4(p), acc0, 0, 0, 0);
            }
            ka = kan; va = van;
        }
    }

    float4 a0; a0.x=acc0[0]; a0.y=acc0[1]; a0.z=acc0[2]; a0.w=acc0[3];
    float4 a1; a1.x=acc1[0]; a1.y=acc1[1]; a1.z=acc1[2]; a1.w=acc1[3];
    accbuf[((size_t)unit*2 + 0)*64 + lane] = a0;
    accbuf[((size_t)unit*2 + 1)*64 + lane] = a1;
    lbuf[((size_t)unit*2 + 0)*64 + lane] = l0;
    lbuf[((size_t)unit*2 + 1)*64 + lane] = l1;
}

// ---------------------------------------------------------------------------
// K3: reduction: one wave per (bh, qp) sums <=8 chunk partials, normalizes,
// writes f16 O. (R9-proven; 576 blocks.)
// ---------------------------------------------------------------------------
__global__ __launch_bounds__(256) void attn_red(
    const float4* __restrict__ accbuf, const float* __restrict__ lbuf,
    f16_t* __restrict__ Of)
{
    const int wid = blockIdx.x*4 + (threadIdx.x >> 6);    // 0..2303
    const int lane = threadIdx.x & 63;
    const int n = lane & 15, quad = lane >> 4;
    const int bh = wid >> 6, qp = wid & 63;
    const int b = bh / NHEADS, h = bh - b*NHEADS;
    const int g = qp >> 3, j = qp & 7;
    const int nch = g + 1;
    const int ubase = bh*288 + qp + 4*g*(g-1) + g*j;

    #pragma unroll
    for (int t = 0; t < 2; t++) {
        float4 a = {0.f, 0.f, 0.f, 0.f};
        float l = 0.f;
        for (int c = 0; c < nch; c++) {
            size_t idx = ((size_t)(ubase + c)*2 + t)*64 + lane;
            float4 v = accbuf[idx];
            a.x += v.x; a.y += v.y; a.z += v.z; a.w += v.w;
            l += lbuf[idx];
        }
        l += __shfl_xor(l, 16, 64);
        l += __shfl_xor(l, 32, 64);
        float inv = 1.0f / l;
        half4v o;
        o[0]=(f16_t)(a.x*inv); o[1]=(f16_t)(a.y*inv);
        o[2]=(f16_t)(a.z*inv); o[3]=(f16_t)(a.w*inv);
        *(half4v*)(Of + (size_t)(b*SEQ + qp*32 + t*16 + n)*H_DIM + h*HEAD_D + quad*4) = o;
    }
}

// ---------------------------------------------------------------------------
// K4: output projection via MFMA (R9-proven). Tile M=32 x N=48, grid (6,128).
// ---------------------------------------------------------------------------
__global__ __launch_bounds__(64) void out_mfma(
    const f16_t* __restrict__ Of, const f16_t* __restrict__ Wo16,
    float* __restrict__ C)
{
    const int n0 = blockIdx.x * 48;
    const int m0 = blockIdx.y * 32;
    const int lane = threadIdx.x & 63;
    const int n = lane & 15, quad = lane >> 4;

    float4v acc[2][3];
    #pragma unroll
    for (int mt = 0; mt < 2; mt++)
        #pragma unroll
        for (int nt = 0; nt < 3; nt++)
            acc[mt][nt] = (float4v){0.f,0.f,0.f,0.f};

    for (int k0 = 0; k0 < H_DIM; k0 += 32) {
        half8v a[2], b[3];
        #pragma unroll
        for (int mt = 0; mt < 2; mt++)
            a[mt] = *(const half8v*)(Of + (size_t)(m0 + mt*16 + n)*H_DIM + k0 + quad*8);
        #pragma unroll
        for (int nt = 0; nt < 3; nt++)
            b[nt] = *(const half8v*)(Wo16 + (size_t)(n0 + nt*16 + n)*H_DIM + k0 + quad*8);
        #pragma unroll
        for (int mt = 0; mt < 2; mt++)
            #pragma unroll
            for (int nt = 0; nt < 3; nt++)
                acc[mt][nt] = __builtin_amdgcn_mfma_f32_16x16x32_f16(a[mt], b[nt], acc[mt][nt], 0, 0, 0);
    }
    #pragma unroll
    for (int mt = 0; mt < 2; mt++)
        #pragma unroll
        for (int nt = 0; nt < 3; nt++)
            #pragma unroll
            for (int r = 0; r < 4; r++) {
                int m = m0 + mt*16 + quad*4 + r;
                C[(size_t)m*H_DIM + n0 + nt*16 + n] = acc[mt][nt][r];
            }
}

// ---------------------------------------------------------------------------
extern "C" void kernel_launch(void* const* d_in, const int* in_sizes, int n_in,
                              void* d_out, int out_size, void* d_ws, size_t ws_size,
                              hipStream_t stream)
{
    const float* Xh = (const float*)d_in[0];
    const float* Wq = (const float*)d_in[1];
    const float* Wk = (const float*)d_in[2];
    const float* Wv = (const float*)d_in[3];
    const float* Wo = (const float*)d_in[4];
    float* out = (float*)d_out;

    f16_t* Xf  = (f16_t*)d_ws;                  // XCNT
    f16_t* Wf  = Xf + XCNT;                     // 4*WCNT
    f16_t* Q16 = Wf + 4*(size_t)WCNT;           // XCNT
    f16_t* K16 = Q16 + XCNT;                    // XCNT
    f16_t* Vt  = K16 + XCNT;                    // XCNT
    f16_t* Of  = Vt + XCNT;                     // XCNT
    float4* accbuf = (float4*)(Of + XCNT);      // NUNITS*2*64 float4
    float*  lbuf   = (float*)(accbuf + (size_t)NUNITS*2*64);

    const int total4 = (XCNT + 4*WCNT)/4;
    cvt_f16<<<dim3((total4 + 255)/256), 256, 0, stream>>>(Xh, Wq, Wk, Wv, Wo, Xf, Wf);
    qkv_mfma<<<dim3(18, 128), 64, 0, stream>>>(Xf, Wf, Q16, K16, Vt);
    attn_part<<<dim3(NUNITS/4), 256, 0, stream>>>(Q16, K16, Vt, accbuf, lbuf);
    attn_red<<<dim3(NQUNITS/4), 256, 0, stream>>>(accbuf, lbuf, Of);
    out_mfma<<<dim3(6, 128), 64, 0, stream>>>(Of, Wf + 3*(size_t)WCNT, out);
}